// Round 1
// baseline (178.551 us; speedup 1.0000x reference)
//
#include <hip/hip_runtime.h>
#include <hip/hip_bf16.h>
#include <stdint.h>

// B=4096, IN=H=1024.  A2 = [x|h] (4096 x 2048 bf16), Wbig (4096 x 2048 bf16):
//   rows    0..2047 : [W_ih_rz | W_rzh]          -> K range [0,2048)   (r, z combined x+h proj)
//   rows 2048..3071 : [W_ih_n  | ------]         -> K range [0,1024)   (n_x)
//   rows 3072..4095 : [------- | W_nh  ]         -> K range [1024,2048) (n_h)
// proj = A2 * Wbig^T  (4096 x 4096, stored bf16 in ws), then fused gate epilogue.

typedef __attribute__((ext_vector_type(8))) short bfrag8;
typedef __attribute__((ext_vector_type(4))) float f32x4;

__device__ __forceinline__ unsigned short f2bf(float f) {
  union { float f; unsigned u; } v; v.f = f;
  unsigned u = v.u;
  return (unsigned short)((u + 0x7fffu + ((u >> 16) & 1u)) >> 16);  // RNE
}

__device__ __forceinline__ float bf2f(unsigned short s) {
  union { unsigned u; float f; } v; v.u = ((unsigned)s) << 16;
  return v.f;
}

__device__ __forceinline__ void load_lds16(const void* g, void* l) {
  __builtin_amdgcn_global_load_lds(
      (const __attribute__((address_space(1))) void*)g,
      (__attribute__((address_space(3))) void*)l, 16, 0, 0);
}

// ---------------- prep A2 = bf16([x | h]) : 4096 x 2048 ----------------
__global__ void prep_a2(const float* __restrict__ x, const float* __restrict__ h,
                        unsigned short* __restrict__ A2) {
  int idx = blockIdx.x * blockDim.x + threadIdx.x;  // 1M threads, 8 elems each
  int j = idx << 3;
  int b = j >> 11;
  int c = j & 2047;
  const float* src = (c < 1024) ? (x + (size_t)b * 1024 + c)
                                : (h + (size_t)b * 1024 + (c - 1024));
  float4 f0 = ((const float4*)src)[0];
  float4 f1 = ((const float4*)src)[1];
  uint4 o;
  o.x = (unsigned)f2bf(f0.x) | ((unsigned)f2bf(f0.y) << 16);
  o.y = (unsigned)f2bf(f0.z) | ((unsigned)f2bf(f0.w) << 16);
  o.z = (unsigned)f2bf(f1.x) | ((unsigned)f2bf(f1.y) << 16);
  o.w = (unsigned)f2bf(f1.z) | ((unsigned)f2bf(f1.w) << 16);
  *(uint4*)(A2 + j) = o;
}

// ---------------- prep Wbig : 4096 x 2048 ----------------
__global__ void prep_w(const float* __restrict__ W_ih, const float* __restrict__ W_rzh,
                       const float* __restrict__ W_nh, unsigned short* __restrict__ Wb) {
  int idx = blockIdx.x * blockDim.x + threadIdx.x;  // 1M threads, 8 elems each
  int j = idx << 3;
  int n = j >> 11;
  int c = j & 2047;
  const float* src = nullptr;
  if (n < 2048) {
    src = (c < 1024) ? (W_ih + (size_t)n * 1024 + c)
                     : (W_rzh + (size_t)n * 1024 + (c - 1024));
  } else if (n < 3072) {
    if (c < 1024) src = W_ih + (size_t)n * 1024 + c;
  } else {
    if (c >= 1024) src = W_nh + (size_t)(n - 3072) * 1024 + (c - 1024);
  }
  uint4 o;
  if (src) {
    float4 f0 = ((const float4*)src)[0];
    float4 f1 = ((const float4*)src)[1];
    o.x = (unsigned)f2bf(f0.x) | ((unsigned)f2bf(f0.y) << 16);
    o.y = (unsigned)f2bf(f0.z) | ((unsigned)f2bf(f0.w) << 16);
    o.z = (unsigned)f2bf(f1.x) | ((unsigned)f2bf(f1.y) << 16);
    o.w = (unsigned)f2bf(f1.z) | ((unsigned)f2bf(f1.w) << 16);
  } else {
    o.x = 0; o.y = 0; o.z = 0; o.w = 0;
  }
  *(uint4*)(Wb + j) = o;
}

// ---------------- GEMM: proj[m,n] = sum_k A2[m,k] * Wb[n,k]  (bf16 in, bf16 out) ----
// 128x128 block tile, BK=32, 256 threads = 4 waves (2x2 of 64x64),
// each wave: 4x4 tiles of mfma_f32_16x16x32_bf16.
__global__ void gemm_proj(const unsigned short* __restrict__ A2,
                          const unsigned short* __restrict__ Wb,
                          unsigned short* __restrict__ proj) {
  __shared__ unsigned short ldsA[128 * 32];  // 8 KB, row-major, 64B rows
  __shared__ unsigned short ldsB[128 * 32];  // 8 KB

  const int tid = threadIdx.x;
  const int lane = tid & 63;
  const int wave = tid >> 6;
  const int bm = blockIdx.x;       // 0..31 (rows of proj)
  const int bn = blockIdx.y;       // 0..31 (cols of proj)
  const int row0 = bm << 7;
  const int col0 = bn << 7;

  int k_begin = (bn >= 24) ? 1024 : 0;
  int k_end   = (bn >= 16 && bn < 24) ? 1024 : 2048;

  const int wm = (wave >> 1) << 6;   // wave row offset in tile
  const int wn = (wave & 1) << 6;    // wave col offset in tile
  const int r = lane & 15;
  const int q = lane >> 4;

  f32x4 acc[4][4] = {};

  // staging: each instr covers 16 rows x 64B; lane L -> row L>>2, 16B-chunk L&3.
  const int srow = wave << 4;        // wave handles rows [srow,srow+16) and [srow+64,+16)
  const int lrow = lane >> 2;
  const int lq = lane & 3;
  const unsigned short* gA0 = A2 + (size_t)(row0 + srow + lrow) * 2048 + lq * 8;
  const unsigned short* gA1 = A2 + (size_t)(row0 + srow + 64 + lrow) * 2048 + lq * 8;
  const unsigned short* gB0 = Wb + (size_t)(col0 + srow + lrow) * 2048 + lq * 8;
  const unsigned short* gB1 = Wb + (size_t)(col0 + srow + 64 + lrow) * 2048 + lq * 8;
  unsigned short* lA0 = &ldsA[srow * 32];
  unsigned short* lA1 = &ldsA[(srow + 64) * 32];
  unsigned short* lB0 = &ldsB[srow * 32];
  unsigned short* lB1 = &ldsB[(srow + 64) * 32];

  for (int k0 = k_begin; k0 < k_end; k0 += 32) {
    __syncthreads();
    load_lds16(gA0 + k0, lA0);
    load_lds16(gA1 + k0, lA1);
    load_lds16(gB0 + k0, lB0);
    load_lds16(gB1 + k0, lB1);
    __syncthreads();

    bfrag8 af[4], bfr[4];
#pragma unroll
    for (int t = 0; t < 4; ++t)
      af[t] = *(const bfrag8*)&ldsA[(wm + t * 16 + r) * 32 + q * 8];
#pragma unroll
    for (int u = 0; u < 4; ++u)
      bfr[u] = *(const bfrag8*)&ldsB[(wn + u * 16 + r) * 32 + q * 8];
#pragma unroll
    for (int t = 0; t < 4; ++t)
#pragma unroll
      for (int u = 0; u < 4; ++u)
        acc[t][u] = __builtin_amdgcn_mfma_f32_16x16x32_bf16(af[t], bfr[u], acc[t][u], 0, 0, 0);
  }

  // C/D layout: col = lane&15, row = (lane>>4)*4 + reg
#pragma unroll
  for (int t = 0; t < 4; ++t) {
    int m = row0 + wm + t * 16 + q * 4;
#pragma unroll
    for (int u = 0; u < 4; ++u) {
      int n = col0 + wn + u * 16 + r;
#pragma unroll
      for (int i = 0; i < 4; ++i)
        proj[(size_t)(m + i) * 4096 + n] = f2bf(acc[t][u][i]);
    }
  }
}

// ---------------- fused gate epilogue ----------------
__global__ void gru_epilogue(const unsigned short* __restrict__ proj,
                             const float* __restrict__ h,
                             const float* __restrict__ b_ih,
                             const float* __restrict__ b_nh,
                             float* __restrict__ out) {
  int idx = blockIdx.x * blockDim.x + threadIdx.x;  // 1M threads, 4 elems each
  int flat = idx << 2;
  int b = flat >> 10;
  int j = flat & 1023;
  const unsigned short* prow = proj + ((size_t)b << 12);
  ushort4 v_rz = *(const ushort4*)(prow + j);
  ushort4 v_zz = *(const ushort4*)(prow + 1024 + j);
  ushort4 v_nx = *(const ushort4*)(prow + 2048 + j);
  ushort4 v_nh = *(const ushort4*)(prow + 3072 + j);
  float4 hv = *(const float4*)(h + ((size_t)b << 10) + j);
  float4 br = *(const float4*)(b_ih + j);
  float4 bz = *(const float4*)(b_ih + 1024 + j);
  float4 bn = *(const float4*)(b_ih + 2048 + j);
  float4 bh = *(const float4*)(b_nh + j);

  float rzv[4] = {bf2f(v_rz.x), bf2f(v_rz.y), bf2f(v_rz.z), bf2f(v_rz.w)};
  float zzv[4] = {bf2f(v_zz.x), bf2f(v_zz.y), bf2f(v_zz.z), bf2f(v_zz.w)};
  float nxv[4] = {bf2f(v_nx.x), bf2f(v_nx.y), bf2f(v_nx.z), bf2f(v_nx.w)};
  float nhv[4] = {bf2f(v_nh.x), bf2f(v_nh.y), bf2f(v_nh.z), bf2f(v_nh.w)};
  float hvv[4] = {hv.x, hv.y, hv.z, hv.w};
  float brv[4] = {br.x, br.y, br.z, br.w};
  float bzv[4] = {bz.x, bz.y, bz.z, bz.w};
  float bnv[4] = {bn.x, bn.y, bn.z, bn.w};
  float bhv[4] = {bh.x, bh.y, bh.z, bh.w};

  float o[4];
#pragma unroll
  for (int i = 0; i < 4; ++i) {
    float rg = 1.f / (1.f + __expf(-(rzv[i] + brv[i])));
    float zg = 1.f / (1.f + __expf(-(zzv[i] + bzv[i])));
    float ng = tanhf(nxv[i] + bnv[i] + rg * (nhv[i] + bhv[i]));
    o[i] = ng + zg * (hvv[i] - ng);
  }
  float4 ov; ov.x = o[0]; ov.y = o[1]; ov.z = o[2]; ov.w = o[3];
  *(float4*)(out + ((size_t)b << 10) + j) = ov;
}

extern "C" void kernel_launch(void* const* d_in, const int* in_sizes, int n_in,
                              void* d_out, int out_size, void* d_ws, size_t ws_size,
                              hipStream_t stream) {
  const float* x     = (const float*)d_in[0];
  const float* h     = (const float*)d_in[1];
  const float* W_ih  = (const float*)d_in[2];
  const float* b_ih  = (const float*)d_in[3];
  const float* W_rzh = (const float*)d_in[4];
  const float* W_nh  = (const float*)d_in[5];
  const float* b_nh  = (const float*)d_in[6];
  float* out = (float*)d_out;

  unsigned short* A2   = (unsigned short*)d_ws;                 // 16 MB
  unsigned short* Wb   = A2 + (size_t)4096 * 2048;              // 16 MB
  unsigned short* proj = Wb + (size_t)4096 * 2048;              // 32 MB

  prep_a2<<<dim3(4096), dim3(256), 0, stream>>>(x, h, A2);
  prep_w<<<dim3(4096), dim3(256), 0, stream>>>(W_ih, W_rzh, W_nh, Wb);
  gemm_proj<<<dim3(32, 32), dim3(256), 0, stream>>>(A2, Wb, proj);
  gru_epilogue<<<dim3(4096), dim3(256), 0, stream>>>(proj, h, b_ih, b_nh, out);
}

// Round 2
// 177.654 us; speedup vs baseline: 1.0051x; 1.0051x over previous
//
#include <hip/hip_runtime.h>
#include <hip/hip_bf16.h>
#include <stdint.h>

// GRU cell, B=4096, IN=H=1024, fp32 in/out, bf16 MFMA internally.
//
// A2 = [x|h] (4096 x 2048 bf16).
// Wb (4096 rows x 2048 bf16), rows in groups of 16: group g = row>>4,
//   segment s = g&3 (0=r,1=z,2=nx,3=nh), h-col j = (g>>2)*16 + (row&15).
//   s=0: K[0,1024)=W_ih[j],      K[1024,2048)=W_rzh[j]
//   s=1: K[0,1024)=W_ih[1024+j], K[1024,2048)=W_rzh[1024+j]
//   s=2: K[0,1024)=W_ih[2048+j]  (upper half never read)
//   s=3: K[1024,2048)=W_nh[j]    (lower half never read)
// GEMM block = 128 batch-rows x 128 cols (= 32 h-cols x 4 segments).
// K-loop: 32 iters over k0 in [0,1024); stages A window0 (x, at k0) and
// window1 (h, at 1024+k0); r/z tiles consume both windows, nx window0 only,
// nh window1 only -> zero padding FLOPs. Gate epilogue fused in-register
// (all 4 segment tiles share the same C/D lane mapping), writes out directly.

typedef __attribute__((ext_vector_type(8))) short bfrag8;
typedef __attribute__((ext_vector_type(4))) float f32x4;

__device__ __forceinline__ unsigned short f2bf(float f) {
  union { float f; unsigned u; } v; v.f = f;
  unsigned u = v.u;
  return (unsigned short)((u + 0x7fffu + ((u >> 16) & 1u)) >> 16);  // RNE
}

__device__ __forceinline__ void load_lds16(const void* g, void* l) {
  __builtin_amdgcn_global_load_lds(
      (const __attribute__((address_space(1))) void*)g,
      (__attribute__((address_space(3))) void*)l, 16, 0, 0);
}

__device__ __forceinline__ void cvt8(const float* __restrict__ src,
                                     unsigned short* __restrict__ dst) {
  float4 f0 = ((const float4*)src)[0];
  float4 f1 = ((const float4*)src)[1];
  uint4 o;
  o.x = (unsigned)f2bf(f0.x) | ((unsigned)f2bf(f0.y) << 16);
  o.y = (unsigned)f2bf(f0.z) | ((unsigned)f2bf(f0.w) << 16);
  o.z = (unsigned)f2bf(f1.x) | ((unsigned)f2bf(f1.y) << 16);
  o.w = (unsigned)f2bf(f1.z) | ((unsigned)f2bf(f1.w) << 16);
  *(uint4*)dst = o;
}

// ---------------- fused prep: A2 and Wb ----------------
__global__ void prep_all(const float* __restrict__ x, const float* __restrict__ h,
                         const float* __restrict__ W_ih, const float* __restrict__ W_rzh,
                         const float* __restrict__ W_nh,
                         unsigned short* __restrict__ A2, unsigned short* __restrict__ Wb) {
  int idx = blockIdx.x * blockDim.x + threadIdx.x;  // 2M threads, 8 elems each
  if (idx < (1 << 20)) {
    int j = idx << 3;
    int b = j >> 11;
    int c = j & 2047;
    const float* src = (c < 1024) ? (x + (size_t)b * 1024 + c)
                                  : (h + (size_t)b * 1024 + (c - 1024));
    cvt8(src, A2 + j);
  } else {
    int j2 = (idx - (1 << 20)) << 3;
    int row = j2 >> 11;
    int c = j2 & 2047;
    int g = row >> 4;
    int s = g & 3;
    int jc = ((g >> 2) << 4) + (row & 15);
    const float* src = nullptr;
    if (s == 0)      src = (c < 1024) ? (W_ih + (size_t)jc * 1024 + c)
                                      : (W_rzh + (size_t)jc * 1024 + (c - 1024));
    else if (s == 1) src = (c < 1024) ? (W_ih + (size_t)(1024 + jc) * 1024 + c)
                                      : (W_rzh + (size_t)(1024 + jc) * 1024 + (c - 1024));
    else if (s == 2) { if (c < 1024)  src = W_ih + (size_t)(2048 + jc) * 1024 + c; }
    else             { if (c >= 1024) src = W_nh + (size_t)jc * 1024 + (c - 1024); }
    if (src) cvt8(src, Wb + j2);
  }
}

// ---------------- fused GEMM + GRU gates ----------------
__global__ void gru_gemm_fused(const unsigned short* __restrict__ A2,
                               const unsigned short* __restrict__ Wb,
                               const float* __restrict__ h,
                               const float* __restrict__ b_ih,
                               const float* __restrict__ b_nh,
                               float* __restrict__ out) {
  __shared__ unsigned short ldsA[2 * 128 * 32];  // 16 KB: [win][row][32]
  __shared__ unsigned short ldsB[12 * 16 * 32];  // 12 KB: [item][row][32]

  const int tid = threadIdx.x;
  const int lane = tid & 63;
  const int wave = tid >> 6;
  const int bm = blockIdx.x;  // 32
  const int bn = blockIdx.y;  // 32
  const int row0 = bm << 7;

  const int r = lane & 15;
  const int q = lane >> 4;
  const int wm = (wave >> 1) << 6;
  const int whalf = wave & 1;

  // staging lane decomposition + XOR bank swizzle (physical chunk = lq holds
  // logical chunk lq ^ ((lrow>>1)&3); fragment reads use q ^ ((r>>1)&3))
  const int lrow = lane >> 2;
  const int lq = lane & 3;
  const int sq = lq ^ ((lrow >> 1) & 3);

  // A staging: 4 instrs/wave (2 windows x 2 row-chunks)
  const unsigned short* gA[4];
  unsigned short* lA[4];
#pragma unroll
  for (int wi = 0; wi < 2; ++wi)
#pragma unroll
    for (int ci = 0; ci < 2; ++ci) {
      int c = wave * 2 + ci;
      gA[wi * 2 + ci] = A2 + (size_t)(row0 + c * 16 + lrow) * 2048 + wi * 1024 + sq * 8;
      lA[wi * 2 + ci] = &ldsA[wi * 4096 + c * 512];
    }

  // B staging: 3 instrs/wave; 12 items = win0 groups {0,1,2,4,5,6}, win1 {0,1,3,4,5,7}
  const unsigned short* gB[3];
  unsigned short* lB[3];
#pragma unroll
  for (int i = 0; i < 3; ++i) {
    int item = wave * 3 + i;
    int wi = (item >= 6) ? 1 : 0;
    int pos = item - wi * 6;
    int hh = (pos >= 3) ? 1 : 0;
    int u2 = pos - hh * 3;
    int g = hh * 4 + ((wi && u2 == 2) ? 3 : u2);
    gB[i] = Wb + (size_t)(bn * 128 + g * 16 + lrow) * 2048 + wi * 1024 + sq * 8;
    lB[i] = &ldsB[item * 512];
  }

  // fragment read offsets (shorts); qs = swizzled chunk * 8
  const int qs = (q ^ ((r >> 1) & 3)) * 8;
  const int base3 = whalf * 3;

  f32x4 acc[4][4] = {};  // [t][segment]

  for (int k0 = 0; k0 < 1024; k0 += 32) {
    __syncthreads();
#pragma unroll
    for (int i = 0; i < 4; ++i) load_lds16(gA[i] + k0, lA[i]);
#pragma unroll
    for (int i = 0; i < 3; ++i) load_lds16(gB[i] + k0, lB[i]);
    __syncthreads();

    bfrag8 af0[4], af1[4];
#pragma unroll
    for (int t = 0; t < 4; ++t) {
      af0[t] = *(const bfrag8*)&ldsA[(wm + t * 16 + r) * 32 + qs];
      af1[t] = *(const bfrag8*)&ldsA[4096 + (wm + t * 16 + r) * 32 + qs];
    }
    bfrag8 b_r0 = *(const bfrag8*)&ldsB[(base3 + 0) * 512 + r * 32 + qs];
    bfrag8 b_z0 = *(const bfrag8*)&ldsB[(base3 + 1) * 512 + r * 32 + qs];
    bfrag8 b_nx = *(const bfrag8*)&ldsB[(base3 + 2) * 512 + r * 32 + qs];
    bfrag8 b_r1 = *(const bfrag8*)&ldsB[(6 + base3 + 0) * 512 + r * 32 + qs];
    bfrag8 b_z1 = *(const bfrag8*)&ldsB[(6 + base3 + 1) * 512 + r * 32 + qs];
    bfrag8 b_nh = *(const bfrag8*)&ldsB[(6 + base3 + 2) * 512 + r * 32 + qs];

#pragma unroll
    for (int t = 0; t < 4; ++t) {
      acc[t][0] = __builtin_amdgcn_mfma_f32_16x16x32_bf16(af0[t], b_r0, acc[t][0], 0, 0, 0);
      acc[t][0] = __builtin_amdgcn_mfma_f32_16x16x32_bf16(af1[t], b_r1, acc[t][0], 0, 0, 0);
      acc[t][1] = __builtin_amdgcn_mfma_f32_16x16x32_bf16(af0[t], b_z0, acc[t][1], 0, 0, 0);
      acc[t][1] = __builtin_amdgcn_mfma_f32_16x16x32_bf16(af1[t], b_z1, acc[t][1], 0, 0, 0);
      acc[t][2] = __builtin_amdgcn_mfma_f32_16x16x32_bf16(af0[t], b_nx, acc[t][2], 0, 0, 0);
      acc[t][3] = __builtin_amdgcn_mfma_f32_16x16x32_bf16(af1[t], b_nh, acc[t][3], 0, 0, 0);
    }
  }

  // fused gate epilogue. C/D layout: col = lane&15 (=r), row = q*4 + reg.
  const int jcol = bn * 32 + whalf * 16 + r;
  const float br = b_ih[jcol];
  const float bz = b_ih[1024 + jcol];
  const float bnv = b_ih[2048 + jcol];
  const float bh = b_nh[jcol];

#pragma unroll
  for (int t = 0; t < 4; ++t) {
    int mbase = row0 + wm + t * 16 + q * 4;
#pragma unroll
    for (int i = 0; i < 4; ++i) {
      size_t off = (size_t)(mbase + i) * 1024 + jcol;
      float rg = 1.f / (1.f + __expf(-(acc[t][0][i] + br)));
      float zg = 1.f / (1.f + __expf(-(acc[t][1][i] + bz)));
      float e2 = __expf(2.f * (acc[t][2][i] + bnv + rg * (acc[t][3][i] + bh)));
      float ng = 1.f - 2.f / (e2 + 1.f);  // tanh
      float hv = h[off];
      out[off] = ng + zg * (hv - ng);
    }
  }
}

extern "C" void kernel_launch(void* const* d_in, const int* in_sizes, int n_in,
                              void* d_out, int out_size, void* d_ws, size_t ws_size,
                              hipStream_t stream) {
  const float* x     = (const float*)d_in[0];
  const float* h     = (const float*)d_in[1];
  const float* W_ih  = (const float*)d_in[2];
  const float* b_ih  = (const float*)d_in[3];
  const float* W_rzh = (const float*)d_in[4];
  const float* W_nh  = (const float*)d_in[5];
  const float* b_nh  = (const float*)d_in[6];
  float* out = (float*)d_out;

  unsigned short* A2 = (unsigned short*)d_ws;          // 16 MB
  unsigned short* Wb = A2 + (size_t)4096 * 2048;       // 16 MB

  prep_all<<<dim3(8192), dim3(256), 0, stream>>>(x, h, W_ih, W_rzh, W_nh, A2, Wb);
  gru_gemm_fused<<<dim3(32, 32), dim3(256), 0, stream>>>(A2, Wb, h, b_ih, b_nh, out);
}

// Round 3
// 168.203 us; speedup vs baseline: 1.0615x; 1.0562x over previous
//
#include <hip/hip_runtime.h>
#include <hip/hip_bf16.h>
#include <stdint.h>

// GRU cell, B=4096, IN=H=1024, fp32 in/out, bf16 MFMA (32x32x16) internally.
//
// A2 = [x|h] (4096 x 2048 bf16).
// Wb (4096 x 2048 bf16), rows in groups of 32: g = row>>5, s = g&3
// (0=r,1=z,2=nx,3=nh), h-col j = (g>>2)*32 + (row&31).
//   s=0: K[0,1024)=W_ih[j],      K[1024,2048)=W_rzh[j]
//   s=1: K[0,1024)=W_ih[1024+j], K[1024,2048)=W_rzh[1024+j]
//   s=2: K[0,1024)=W_ih[2048+j]  (upper K half never read)
//   s=3: K[1024,2048)=W_nh[j]    (lower K half never read)
// GEMM block = 256 M x 128 N (32 h-cols x 4 segments); 4 waves, each
// 64M x 128N = 2x4 tiles of mfma_f32_32x32x16_bf16 (acc 128 VGPR).
// K-loop: 32 iters of K=32 staging both A windows (x @ k0, h @ 1024+k0)
// and 6 B items; r/z consume both windows, nx win0, nh win1 -> no padding
// FLOPs. Gate epilogue fused in-register (all 4 segment tiles share the
// 32x32 C/D lane mapping: col=lane&31, row=(reg&3)+8*(reg>>2)+4*(lane>>5)).
// LDS XOR swizzle: physical 16B chunk = logical ^ ((row>>1)&3) -> 0 bank
// conflicts (verified by counter in round 2 for the 16-row variant).

typedef __attribute__((ext_vector_type(8))) short bfrag8;
typedef __attribute__((ext_vector_type(16))) float f32x16;

__device__ __forceinline__ unsigned short f2bf(float f) {
  union { float f; unsigned u; } v; v.f = f;
  unsigned u = v.u;
  return (unsigned short)((u + 0x7fffu + ((u >> 16) & 1u)) >> 16);  // RNE
}

__device__ __forceinline__ void load_lds16(const void* g, void* l) {
  __builtin_amdgcn_global_load_lds(
      (const __attribute__((address_space(1))) void*)g,
      (__attribute__((address_space(3))) void*)l, 16, 0, 0);
}

__device__ __forceinline__ void cvt8(const float* __restrict__ src,
                                     unsigned short* __restrict__ dst) {
  float4 f0 = ((const float4*)src)[0];
  float4 f1 = ((const float4*)src)[1];
  uint4 o;
  o.x = (unsigned)f2bf(f0.x) | ((unsigned)f2bf(f0.y) << 16);
  o.y = (unsigned)f2bf(f0.z) | ((unsigned)f2bf(f0.w) << 16);
  o.z = (unsigned)f2bf(f1.x) | ((unsigned)f2bf(f1.y) << 16);
  o.w = (unsigned)f2bf(f1.z) | ((unsigned)f2bf(f1.w) << 16);
  *(uint4*)dst = o;
}

// ---------------- fused prep: A2 and Wb ----------------
__global__ void prep_all(const float* __restrict__ x, const float* __restrict__ h,
                         const float* __restrict__ W_ih, const float* __restrict__ W_rzh,
                         const float* __restrict__ W_nh,
                         unsigned short* __restrict__ A2, unsigned short* __restrict__ Wb) {
  int idx = blockIdx.x * blockDim.x + threadIdx.x;  // 2M threads, 8 elems each
  if (idx < (1 << 20)) {
    int j = idx << 3;
    int b = j >> 11;
    int c = j & 2047;
    const float* src = (c < 1024) ? (x + (size_t)b * 1024 + c)
                                  : (h + (size_t)b * 1024 + (c - 1024));
    cvt8(src, A2 + j);
  } else {
    int j2 = (idx - (1 << 20)) << 3;
    int row = j2 >> 11;
    int c = j2 & 2047;
    int g = row >> 5;
    int s = g & 3;
    int jc = ((g >> 2) << 5) + (row & 31);
    const float* src = nullptr;
    if (s == 0)      src = (c < 1024) ? (W_ih + (size_t)jc * 1024 + c)
                                      : (W_rzh + (size_t)jc * 1024 + (c - 1024));
    else if (s == 1) src = (c < 1024) ? (W_ih + (size_t)(1024 + jc) * 1024 + c)
                                      : (W_rzh + (size_t)(1024 + jc) * 1024 + (c - 1024));
    else if (s == 2) { if (c < 1024)  src = W_ih + (size_t)(2048 + jc) * 1024 + c; }
    else             { if (c >= 1024) src = W_nh + (size_t)jc * 1024 + (c - 1024); }
    if (src) cvt8(src, Wb + j2);
  }
}

// ---------------- fused GEMM (32x32x16) + GRU gates ----------------
__global__ __launch_bounds__(256, 2)
void gru_gemm_fused(const unsigned short* __restrict__ A2,
                    const unsigned short* __restrict__ Wb,
                    const float* __restrict__ h,
                    const float* __restrict__ b_ih,
                    const float* __restrict__ b_nh,
                    float* __restrict__ out) {
  __shared__ unsigned short ldsA[2 * 256 * 32];  // 32 KB: [win][row][32k]
  __shared__ unsigned short ldsB[6 * 32 * 32];   // 12 KB: [item][row][32k]

  const int lane = threadIdx.x & 63;
  const int wave = threadIdx.x >> 6;
  const int row0 = blockIdx.x << 8;  // 16 blocks in M
  const int bn = blockIdx.y;         // 32 blocks in N (h-col groups of 32)

  const int wm = wave << 6;          // wave M offset (64 rows)
  const int m32 = lane & 31;
  const int khalf = lane >> 5;

  // staging lane decomposition + XOR chunk swizzle
  const int lrow = lane >> 2;
  const int lq = lane & 3;
  const int sq = lq ^ ((lrow >> 1) & 3);

  // A staging: 8 instrs/wave (2 win x 4 row-chunks of 16), rows [wm, wm+64)
  const unsigned short* gA[2][4];
  unsigned short* lA[2][4];
#pragma unroll
  for (int win = 0; win < 2; ++win)
#pragma unroll
    for (int ci = 0; ci < 4; ++ci) {
      gA[win][ci] = A2 + (size_t)(row0 + wm + ci * 16 + lrow) * 2048 + win * 1024 + sq * 8;
      lA[win][ci] = &ldsA[win * 8192 + (wm + ci * 16) * 32];
    }

  // B staging: 3 instrs/wave; 12 instrs = 6 items x 2 row-halves.
  // item -> (win, segment): 0:(0,r) 1:(0,z) 2:(0,nx) 3:(1,r) 4:(1,z) 5:(1,nh)
  const int item_win[6] = {0, 0, 0, 1, 1, 1};
  const int item_s[6]   = {0, 1, 2, 0, 1, 3};
  const unsigned short* gB[3];
  unsigned short* lB[3];
#pragma unroll
  for (int i = 0; i < 3; ++i) {
    int j = wave * 3 + i;
    int item = j >> 1;
    int half = j & 1;
    gB[i] = Wb + (size_t)(bn * 128 + item_s[item] * 32 + half * 16 + lrow) * 2048
              + item_win[item] * 1024 + sq * 8;
    lB[i] = &ldsB[item * 1024 + half * 16 * 32];
  }

  f32x16 acc[2][4] = {};  // [t][segment r,z,nx,nh]

  for (int k0 = 0; k0 < 1024; k0 += 32) {
    __syncthreads();
#pragma unroll
    for (int win = 0; win < 2; ++win)
#pragma unroll
      for (int ci = 0; ci < 4; ++ci) load_lds16(gA[win][ci] + k0, lA[win][ci]);
#pragma unroll
    for (int i = 0; i < 3; ++i) load_lds16(gB[i] + k0, lB[i]);
    __syncthreads();

#pragma unroll
    for (int ks = 0; ks < 2; ++ks) {
      // A-frag: lane -> A[m = lane&31][k = khalf*8 + j]; logical chunk = ks*2+khalf
      const int pc = ((ks * 2 + khalf) ^ ((m32 >> 1) & 3)) * 8;
      bfrag8 a0[2], a1[2], bfr[6];
#pragma unroll
      for (int t = 0; t < 2; ++t) {
        a0[t] = *(const bfrag8*)&ldsA[(wm + t * 32 + m32) * 32 + pc];
        a1[t] = *(const bfrag8*)&ldsA[8192 + (wm + t * 32 + m32) * 32 + pc];
      }
#pragma unroll
      for (int it = 0; it < 6; ++it)
        bfr[it] = *(const bfrag8*)&ldsB[it * 1024 + m32 * 32 + pc];

#pragma unroll
      for (int t = 0; t < 2; ++t) {
        acc[t][0] = __builtin_amdgcn_mfma_f32_32x32x16_bf16(a0[t], bfr[0], acc[t][0], 0, 0, 0);
        acc[t][0] = __builtin_amdgcn_mfma_f32_32x32x16_bf16(a1[t], bfr[3], acc[t][0], 0, 0, 0);
        acc[t][1] = __builtin_amdgcn_mfma_f32_32x32x16_bf16(a0[t], bfr[1], acc[t][1], 0, 0, 0);
        acc[t][1] = __builtin_amdgcn_mfma_f32_32x32x16_bf16(a1[t], bfr[4], acc[t][1], 0, 0, 0);
        acc[t][2] = __builtin_amdgcn_mfma_f32_32x32x16_bf16(a0[t], bfr[2], acc[t][2], 0, 0, 0);
        acc[t][3] = __builtin_amdgcn_mfma_f32_32x32x16_bf16(a1[t], bfr[5], acc[t][3], 0, 0, 0);
      }
    }
  }

  // fused gate epilogue. 32x32 C/D: col=lane&31, row=(reg&3)+8*(reg>>2)+4*khalf
  const int jcol = bn * 32 + m32;
  const float br  = b_ih[jcol];
  const float bz  = b_ih[1024 + jcol];
  const float bnv = b_ih[2048 + jcol];
  const float bh  = b_nh[jcol];

#pragma unroll
  for (int t = 0; t < 2; ++t) {
#pragma unroll
    for (int i = 0; i < 16; ++i) {
      int mrow = row0 + wm + t * 32 + (i & 3) + ((i >> 2) << 3) + (khalf << 2);
      size_t off = (size_t)mrow * 1024 + jcol;
      float rg = 1.f / (1.f + __expf(-(acc[t][0][i] + br)));
      float zg = 1.f / (1.f + __expf(-(acc[t][1][i] + bz)));
      float e2 = __expf(2.f * (acc[t][2][i] + bnv + rg * (acc[t][3][i] + bh)));
      float ng = 1.f - 2.f / (e2 + 1.f);  // tanh
      float hv = h[off];
      out[off] = ng + zg * (hv - ng);
    }
  }
}

extern "C" void kernel_launch(void* const* d_in, const int* in_sizes, int n_in,
                              void* d_out, int out_size, void* d_ws, size_t ws_size,
                              hipStream_t stream) {
  const float* x     = (const float*)d_in[0];
  const float* h     = (const float*)d_in[1];
  const float* W_ih  = (const float*)d_in[2];
  const float* b_ih  = (const float*)d_in[3];
  const float* W_rzh = (const float*)d_in[4];
  const float* W_nh  = (const float*)d_in[5];
  const float* b_nh  = (const float*)d_in[6];
  float* out = (float*)d_out;

  unsigned short* A2 = (unsigned short*)d_ws;          // 16 MB
  unsigned short* Wb = A2 + (size_t)4096 * 2048;       // 16 MB

  prep_all<<<dim3(8192), dim3(256), 0, stream>>>(x, h, W_ih, W_rzh, W_nh, A2, Wb);
  gru_gemm_fused<<<dim3(16, 32), dim3(256), 0, stream>>>(A2, Wb, h, b_ih, b_nh, out);
}

// Round 4
// 164.290 us; speedup vs baseline: 1.0868x; 1.0238x over previous
//
#include <hip/hip_runtime.h>
#include <hip/hip_bf16.h>
#include <stdint.h>

// GRU cell, B=4096, IN=H=1024, fp32 in/out, bf16 MFMA (32x32x16) internally.
//
// Fragment-ordered workspace layouts (prep pre-swizzles into MFMA lane order;
// every GEMM ds_read is then base + lane*16 -> structurally conflict-free,
// matching the DMA-write pattern that has measured 0 conflicts):
//
// A2t: chunk idx = ((T*2 + win)*64 + kc)*64 + L, chunk = 16 B (8 bf16).
//   T = m-tile (32 rows, 0..127), win: 0=x, 1=h, kc = k/16 (0..63),
//   L = khalf*32 + m32 -> data = src[T*32+m32][kc*16 + khalf*8 .. +8).
// Wbt: chunk idx = ((bn*6 + item)*64 + kc)*64 + L,
//   item -> (win, gate): 0:(x,r)=W_ih[j], 1:(x,z)=W_ih[1024+j],
//   2:(x,nx)=W_ih[2048+j], 3:(h,r)=W_rzh[j], 4:(h,z)=W_rzh[1024+j],
//   5:(h,nh)=W_nh[j];  j = bn*32 + (L&31), k-col = kc*16 + (L>>5)*8.
//
// GEMM block = 256 M x 128 N; 4 waves x (64M: 2 tiles of 32) x 4 gate
// segments of mfma_f32_32x32x16_bf16 (acc 128 VGPR). K-loop: 32 iters of
// K=32 staging both windows; r/z consume both, nx win0 only, nh win1 only
// -> zero padding FLOPs. Gate epilogue fused in-register
// (32x32 C/D: col=lane&31, row=(reg&3)+8*(reg>>2)+4*(lane>>5)).

typedef __attribute__((ext_vector_type(8))) short bfrag8;
typedef __attribute__((ext_vector_type(16))) float f32x16;

__device__ __forceinline__ unsigned short f2bf(float f) {
  union { float f; unsigned u; } v; v.f = f;
  unsigned u = v.u;
  return (unsigned short)((u + 0x7fffu + ((u >> 16) & 1u)) >> 16);  // RNE
}

__device__ __forceinline__ void load_lds16(const void* g, void* l) {
  __builtin_amdgcn_global_load_lds(
      (const __attribute__((address_space(1))) void*)g,
      (__attribute__((address_space(3))) void*)l, 16, 0, 0);
}

__device__ __forceinline__ void cvt8(const float* __restrict__ src,
                                     unsigned short* __restrict__ dst) {
  float4 f0 = ((const float4*)src)[0];
  float4 f1 = ((const float4*)src)[1];
  uint4 o;
  o.x = (unsigned)f2bf(f0.x) | ((unsigned)f2bf(f0.y) << 16);
  o.y = (unsigned)f2bf(f0.z) | ((unsigned)f2bf(f0.w) << 16);
  o.z = (unsigned)f2bf(f1.x) | ((unsigned)f2bf(f1.y) << 16);
  o.w = (unsigned)f2bf(f1.z) | ((unsigned)f2bf(f1.w) << 16);
  *(uint4*)dst = o;
}

// ---------------- prep: build fragment-ordered A2t and Wbt ----------------
__global__ void prep_all(const float* __restrict__ x, const float* __restrict__ h,
                         const float* __restrict__ W_ih, const float* __restrict__ W_rzh,
                         const float* __restrict__ W_nh,
                         unsigned short* __restrict__ A2t, unsigned short* __restrict__ Wbt) {
  int idx = blockIdx.x * blockDim.x + threadIdx.x;  // [0, 1<<20 + 786432)
  if (idx < (1 << 20)) {
    int L = idx & 63;
    int kc = (idx >> 6) & 63;
    int win = (idx >> 12) & 1;
    int T = idx >> 13;
    int row = T * 32 + (L & 31);
    int col = kc * 16 + (L >> 5) * 8;
    const float* src = (win ? h : x) + (size_t)row * 1024 + col;
    cvt8(src, A2t + (size_t)idx * 8);
  } else {
    int c2 = idx - (1 << 20);
    int L = c2 & 63;
    int kc = (c2 >> 6) & 63;
    int rest = c2 >> 12;        // bn*6 + item, 0..191
    int bn = rest / 6;
    int item = rest - bn * 6;
    int jc = bn * 32 + (L & 31);
    int col = kc * 16 + (L >> 5) * 8;
    const float* src;
    switch (item) {
      case 0:  src = W_ih  + (size_t)jc * 1024 + col; break;
      case 1:  src = W_ih  + (size_t)(1024 + jc) * 1024 + col; break;
      case 2:  src = W_ih  + (size_t)(2048 + jc) * 1024 + col; break;
      case 3:  src = W_rzh + (size_t)jc * 1024 + col; break;
      case 4:  src = W_rzh + (size_t)(1024 + jc) * 1024 + col; break;
      default: src = W_nh  + (size_t)jc * 1024 + col; break;
    }
    cvt8(src, Wbt + (size_t)c2 * 8);
  }
}

// ---------------- fused GEMM (32x32x16) + GRU gates ----------------
__global__ __launch_bounds__(256, 2)
void gru_gemm_fused(const unsigned short* __restrict__ A2t,
                    const unsigned short* __restrict__ Wbt,
                    const float* __restrict__ h,
                    const float* __restrict__ b_ih,
                    const float* __restrict__ b_nh,
                    float* __restrict__ out) {
  // region(r) = 512 shorts = 64 lane-chunks of 16B
  __shared__ unsigned short ldsA[8 * 2 * 2 * 512];  // 32 KB: (Tloc, win, kcl)
  __shared__ unsigned short ldsB[6 * 2 * 512];      // 12 KB: (item, kcl)

  const int lane = threadIdx.x & 63;
  const int wave = threadIdx.x >> 6;
  const int row0 = blockIdx.x << 8;  // 16 blocks in M
  const int bn = blockIdx.y;         // 32 blocks in N

  const int wm = wave << 6;
  const int m32 = lane & 31;
  const int khalf = lane >> 5;

  // A staging: 8 instrs/wave (2 tiles x 2 win x 2 kcl), contiguous 1024B each
  const unsigned short* gA[2][2][2];
  unsigned short* lA[2][2][2];
#pragma unroll
  for (int t = 0; t < 2; ++t)
#pragma unroll
    for (int win = 0; win < 2; ++win)
#pragma unroll
      for (int kcl = 0; kcl < 2; ++kcl) {
        int T = blockIdx.x * 8 + wave * 2 + t;
        gA[t][win][kcl] = A2t + (size_t)(T * 2 + win) * 32768 + kcl * 512 + lane * 8;
        lA[t][win][kcl] = &ldsA[(((wave * 2 + t) * 2 + win) * 2 + kcl) * 512];
      }

  // B staging: 3 instrs/wave (12 total = 6 items x 2 kcl)
  const unsigned short* gB[3];
  unsigned short* lB[3];
#pragma unroll
  for (int i = 0; i < 3; ++i) {
    int j = wave * 3 + i;
    int item = j >> 1;
    int kcl = j & 1;
    gB[i] = Wbt + (size_t)(bn * 6 + item) * 32768 + kcl * 512 + lane * 8;
    lB[i] = &ldsB[(item * 2 + kcl) * 512];
  }

  f32x16 acc[2][4] = {};  // [t][segment r,z,nx,nh]

  for (int k0 = 0; k0 < 1024; k0 += 32) {
    const size_t koff = (size_t)k0 * 32;  // shorts: (k0/16)*512
    __syncthreads();
#pragma unroll
    for (int t = 0; t < 2; ++t)
#pragma unroll
      for (int win = 0; win < 2; ++win)
#pragma unroll
        for (int kcl = 0; kcl < 2; ++kcl)
          load_lds16(gA[t][win][kcl] + koff, lA[t][win][kcl]);
#pragma unroll
    for (int i = 0; i < 3; ++i) load_lds16(gB[i] + koff, lB[i]);
    __syncthreads();

#pragma unroll
    for (int ks = 0; ks < 2; ++ks) {
      const int fo = ks * 512 + lane * 8;
      bfrag8 a0[2], a1[2], bfr[6];
#pragma unroll
      for (int t = 0; t < 2; ++t) {
        a0[t] = *(const bfrag8*)&ldsA[((wave * 2 + t) * 2 + 0) * 1024 + fo];
        a1[t] = *(const bfrag8*)&ldsA[((wave * 2 + t) * 2 + 1) * 1024 + fo];
      }
#pragma unroll
      for (int it = 0; it < 6; ++it)
        bfr[it] = *(const bfrag8*)&ldsB[it * 1024 + fo];

#pragma unroll
      for (int t = 0; t < 2; ++t) {
        acc[t][0] = __builtin_amdgcn_mfma_f32_32x32x16_bf16(a0[t], bfr[0], acc[t][0], 0, 0, 0);
        acc[t][0] = __builtin_amdgcn_mfma_f32_32x32x16_bf16(a1[t], bfr[3], acc[t][0], 0, 0, 0);
        acc[t][1] = __builtin_amdgcn_mfma_f32_32x32x16_bf16(a0[t], bfr[1], acc[t][1], 0, 0, 0);
        acc[t][1] = __builtin_amdgcn_mfma_f32_32x32x16_bf16(a1[t], bfr[4], acc[t][1], 0, 0, 0);
        acc[t][2] = __builtin_amdgcn_mfma_f32_32x32x16_bf16(a0[t], bfr[2], acc[t][2], 0, 0, 0);
        acc[t][3] = __builtin_amdgcn_mfma_f32_32x32x16_bf16(a1[t], bfr[5], acc[t][3], 0, 0, 0);
      }
    }
  }

  // fused gate epilogue. 32x32 C/D: col=lane&31, row=(reg&3)+8*(reg>>2)+4*khalf
  const int jcol = bn * 32 + m32;
  const float br  = b_ih[jcol];
  const float bz  = b_ih[1024 + jcol];
  const float bnv = b_ih[2048 + jcol];
  const float bh  = b_nh[jcol];

#pragma unroll
  for (int t = 0; t < 2; ++t) {
#pragma unroll
    for (int i = 0; i < 16; ++i) {
      int mrow = row0 + wm + t * 32 + (i & 3) + ((i >> 2) << 3) + (khalf << 2);
      size_t off = (size_t)mrow * 1024 + jcol;
      float rg = 1.f / (1.f + __expf(-(acc[t][0][i] + br)));
      float zg = 1.f / (1.f + __expf(-(acc[t][1][i] + bz)));
      float e2 = __expf(2.f * (acc[t][2][i] + bnv + rg * (acc[t][3][i] + bh)));
      float ng = 1.f - 2.f / (e2 + 1.f);  // tanh
      float hv = h[off];
      out[off] = ng + zg * (hv - ng);
    }
  }
}

extern "C" void kernel_launch(void* const* d_in, const int* in_sizes, int n_in,
                              void* d_out, int out_size, void* d_ws, size_t ws_size,
                              hipStream_t stream) {
  const float* x     = (const float*)d_in[0];
  const float* h     = (const float*)d_in[1];
  const float* W_ih  = (const float*)d_in[2];
  const float* b_ih  = (const float*)d_in[3];
  const float* W_rzh = (const float*)d_in[4];
  const float* W_nh  = (const float*)d_in[5];
  const float* b_nh  = (const float*)d_in[6];
  float* out = (float*)d_out;

  unsigned short* A2t = (unsigned short*)d_ws;           // 16 MB (2^20 chunks)
  unsigned short* Wbt = A2t + (size_t)(1 << 20) * 8;     // 12 MB (786432 chunks)

  prep_all<<<dim3(7168), dim3(256), 0, stream>>>(x, h, W_ih, W_rzh, W_nh, A2t, Wbt);
  gru_gemm_fused<<<dim3(16, 32), dim3(256), 0, stream>>>(A2t, Wbt, h, b_ih, b_nh, out);
}